// Round 6
// baseline (1082.937 us; speedup 1.0000x reference)
//
#include <hip/hip_runtime.h>

// RGCN: 2-layer hetero GraphConv, R=4 relations.
// R1: CSR gather. R2: bf16 MFMA GEMM. R3: concat-GEMM + fused gathers.
// R4: layer-1 aggregate-first (gather x, then K=1024 GEMM).
// R5: nontemporal streaming loads (stop L2-thrash of atomic tables / x rows),
//     e_ns stream removed (nsrc table lookup instead), cursor fused into scan.

#define RELS 4
#define DIN 256
#define DHID 256
#define DOUT 128

typedef short short8 __attribute__((ext_vector_type(8)));
typedef float f32x4 __attribute__((ext_vector_type(4)));

// ---- helpers --------------------------------------------------------------

__device__ __forceinline__ unsigned short f2bf(float f) {
    unsigned int u = __float_as_uint(f);
    u += 0x7FFFu + ((u >> 16) & 1u);   // round-to-nearest-even
    return (unsigned short)(u >> 16);
}
__device__ __forceinline__ float bf2f(unsigned short u) {
    return __uint_as_float(((unsigned int)u) << 16);
}

// ---- CSR build --------------------------------------------------------------

__global__ void hist_kernel(const int* __restrict__ src, const int* __restrict__ dst,
                            int* __restrict__ cnt_src, int* __restrict__ cnt_dst,
                            int E, int N) {
    int i = blockIdx.x * blockDim.x + threadIdx.x;
    if (i >= RELS * E) return;
    int r = i / E;
    int s = __builtin_nontemporal_load(src + i);
    int d = __builtin_nontemporal_load(dst + i);
    atomicAdd(cnt_src + (size_t)r * N + s, 1);
    atomicAdd(cnt_dst + (size_t)r * N + d, 1);
}

__global__ void norm_kernel(const int* __restrict__ cnt, float* __restrict__ nrm, long n) {
    long i = blockIdx.x * (long)blockDim.x + threadIdx.x;
    if (i >= n) return;
    nrm[i] = rsqrtf(fmaxf((float)cnt[i], 1.0f));
}

__global__ void scan_block(const int* __restrict__ counts, int* __restrict__ out,
                           int* __restrict__ blk_sums, int n) {
    __shared__ int sh[256];
    int i = blockIdx.x * 256 + threadIdx.x;
    int v = (i < n) ? counts[i] : 0;
    sh[threadIdx.x] = v;
    __syncthreads();
#pragma unroll
    for (int off = 1; off < 256; off <<= 1) {
        int t = (threadIdx.x >= off) ? sh[threadIdx.x - off] : 0;
        __syncthreads();
        sh[threadIdx.x] += t;
        __syncthreads();
    }
    if (i < n) out[i] = sh[threadIdx.x] - v;
    if (threadIdx.x == 255) blk_sums[blockIdx.x] = sh[255];
}

__global__ void scan_sums(int* __restrict__ bs, int nb) {
    __shared__ int sh[256];
    __shared__ int carry;
    if (threadIdx.x == 0) carry = 0;
    __syncthreads();
    for (int base = 0; base < nb; base += 256) {
        int i = base + threadIdx.x;
        int v = (i < nb) ? bs[i] : 0;
        sh[threadIdx.x] = v;
        __syncthreads();
#pragma unroll
        for (int off = 1; off < 256; off <<= 1) {
            int t = (threadIdx.x >= off) ? sh[threadIdx.x - off] : 0;
            __syncthreads();
            sh[threadIdx.x] += t;
            __syncthreads();
        }
        if (i < nb) bs[i] = sh[threadIdx.x] - v + carry;  // exclusive
        int tot = sh[255];
        __syncthreads();
        if (threadIdx.x == 255) carry += tot;
        __syncthreads();
    }
}

// writes row_ptr AND cursor (same values) — cursor_init launch eliminated
__global__ void scan_add(int* __restrict__ out, int* __restrict__ cursor,
                         const int* __restrict__ blk_sums, int n, int total) {
    int i = blockIdx.x * 256 + threadIdx.x;
    if (i < n) {
        int v = out[i] + blk_sums[blockIdx.x];
        out[i] = v;
        cursor[i] = v;
    }
    if (i == n - 1) out[n] = total;
}

// place src into dst-sorted position
__global__ void fill_kernel(const int* __restrict__ src, const int* __restrict__ dst,
                            int* __restrict__ cursor, int* __restrict__ e_src, int E, int N) {
    int i = blockIdx.x * blockDim.x + threadIdx.x;
    if (i >= RELS * E) return;
    int r = i / E;
    int s = __builtin_nontemporal_load(src + i);
    int d = __builtin_nontemporal_load(dst + i);
    int pos = atomicAdd(cursor + (size_t)r * N + d, 1);
    __builtin_nontemporal_store(s, e_src + pos);
}

// ---- dtype conversion --------------------------------------------------------

__global__ void f32_to_bf16_kernel(const float* __restrict__ in,
                                   unsigned short* __restrict__ out, long n8) {
    long i = blockIdx.x * (long)blockDim.x + threadIdx.x;
    if (i >= n8) return;
    const float4* ip = (const float4*)(in + i * 8);
    float4 v0 = ip[0], v1 = ip[1];
    ushort4 o0 = make_ushort4(f2bf(v0.x), f2bf(v0.y), f2bf(v0.z), f2bf(v0.w));
    ushort4 o1 = make_ushort4(f2bf(v1.x), f2bf(v1.y), f2bf(v1.z), f2bf(v1.w));
    ushort4* op = (ushort4*)(out + i * 8);
    op[0] = o0; op[1] = o1;
}

// W1 [R][K][Nout] f32 -> Wt [Nout][R*K] bf16  (K-concat layout for agg-first)
__global__ void w1_transpose_cat(const float* __restrict__ W, unsigned short* __restrict__ Wt,
                                 int K, int Nout) {
    int i = blockIdx.x * blockDim.x + threadIdx.x;
    int total = RELS * K * Nout;
    if (i >= total) return;
    int r = i / (K * Nout);
    int rem = i - r * (K * Nout);
    int k = rem / Nout, n = rem - k * Nout;
    Wt[(size_t)n * (RELS * K) + r * K + k] = f2bf(W[i]);
}

// W2 [R][K][Nout] f32 -> Wt [R*Nout][K] bf16  (N-concat layout for project-first)
__global__ void w2_transpose_cat(const float* __restrict__ W, unsigned short* __restrict__ Wt,
                                 int K, int Nout) {
    int i = blockIdx.x * blockDim.x + threadIdx.x;
    int total = RELS * K * Nout;
    if (i >= total) return;
    int r = i / (K * Nout);
    int rem = i - r * (K * Nout);
    int k = rem / Nout, n = rem - k * Nout;
    Wt[((size_t)r * Nout + n) * K + k] = f2bf(W[i]);
}

__global__ void bias_sum_kernel(const float* __restrict__ b1, const float* __restrict__ b2,
                                float* __restrict__ b1s, float* __restrict__ b2s) {
    int i = blockIdx.x * blockDim.x + threadIdx.x;
    if (i < DHID) {
        b1s[i] = b1[i] + b1[DHID + i] + b1[2 * DHID + i] + b1[3 * DHID + i];
    } else if (i < DHID + DOUT) {
        int c = i - DHID;
        b2s[c] = b2[c] + b2[DOUT + c] + b2[2 * DOUT + c] + b2[3 * DOUT + c];
    }
}

// ---- bf16 MFMA GEMM ---------------------------------------------------------
// BM=BN=128, BK=32, 256 threads (4 waves 2x2), 4x4 frags of 16x16x32/wave.
// LDS [128][32] bf16 per operand, XOR chunk swizzle (both-sides involution).
// MODE 0: C = bf16( acc * nsrc[rel][row] )          (layer-2 project-first)
// MODE 1: C = bf16( relu(acc + bias[col]) )         (layer-1 agg-first)

__device__ __forceinline__ void gload_lds16(const void* g, void* l) {
    __builtin_amdgcn_global_load_lds(
        (const __attribute__((address_space(1))) void*)g,
        (__attribute__((address_space(3))) void*)l, 16, 0, 0);
}

template <int MODE>
__global__ __launch_bounds__(256) void gemm_bf16(
    const unsigned short* __restrict__ A, const unsigned short* __restrict__ Bt,
    unsigned short* __restrict__ C, int M, int Nout, int K,
    const float* __restrict__ scale_or_bias, int cols_per_rel, int Nnodes) {
    __shared__ unsigned short smA[128 * 32];
    __shared__ unsigned short smB[128 * 32];
    const int tid = threadIdx.x;
    const int lane = tid & 63;
    const int wid = tid >> 6;
    const int wr = wid >> 1, wc = wid & 1;
    const int brow = blockIdx.x * 128, bcol = blockIdx.y * 128;

    f32x4 acc[4][4] = {};

    const int s = lane >> 4;
    const int rl = lane & 15;

    for (int k0 = 0; k0 < K; k0 += 32) {
#pragma unroll
        for (int q = 0; q < 2; ++q) {
            int c = q * 256 + tid;
            int cl = c ^ ((c >> 3) & 3);
            int row = cl >> 2, slot = cl & 3;
            int ga = brow + row; ga = ga < M ? ga : M - 1;
            size_t ldsoff = (size_t)(q * 256 + (tid & ~63)) * 16;
            gload_lds16(A + (size_t)ga * K + k0 + slot * 8, (char*)smA + ldsoff);
            gload_lds16(Bt + (size_t)(bcol + row) * K + k0 + slot * 8, (char*)smB + ldsoff);
        }
        asm volatile("s_waitcnt vmcnt(0)" ::: "memory");
        __syncthreads();

        short8 a[4], b[4];
#pragma unroll
        for (int i = 0; i < 4; ++i) {
            int r = wr * 64 + i * 16 + rl;
            int ch = r * 4 + (s ^ ((r >> 1) & 3));
            a[i] = *(const short8*)((const char*)smA + ch * 16);
        }
#pragma unroll
        for (int j = 0; j < 4; ++j) {
            int r = wc * 64 + j * 16 + rl;
            int ch = r * 4 + (s ^ ((r >> 1) & 3));
            b[j] = *(const short8*)((const char*)smB + ch * 16);
        }
#pragma unroll
        for (int i = 0; i < 4; ++i)
#pragma unroll
            for (int j = 0; j < 4; ++j)
                acc[i][j] = __builtin_amdgcn_mfma_f32_16x16x32_bf16(a[i], b[j], acc[i][j], 0, 0, 0);
        __syncthreads();
    }

    const int rq = lane >> 4;
    if (MODE == 0) {
        const int relid = bcol / cols_per_rel;
        const float* nsr = scale_or_bias + (size_t)relid * Nnodes;
#pragma unroll
        for (int i = 0; i < 4; ++i) {
            int rbase = brow + wr * 64 + i * 16 + rq * 4;
            float sc[4];
#pragma unroll
            for (int t = 0; t < 4; ++t) {
                int row = rbase + t;
                sc[t] = (row < M) ? nsr[row] : 0.f;
            }
#pragma unroll
            for (int j = 0; j < 4; ++j) {
                int col = bcol + wc * 64 + j * 16 + rl;
#pragma unroll
                for (int t = 0; t < 4; ++t) {
                    int row = rbase + t;
                    if (row < M) C[(size_t)row * Nout + col] = f2bf(acc[i][j][t] * sc[t]);
                }
            }
        }
    } else {
#pragma unroll
        for (int i = 0; i < 4; ++i) {
            int rbase = brow + wr * 64 + i * 16 + rq * 4;
#pragma unroll
            for (int j = 0; j < 4; ++j) {
                int col = bcol + wc * 64 + j * 16 + rl;
                float bb = scale_or_bias[col];
#pragma unroll
                for (int t = 0; t < 4; ++t) {
                    int row = rbase + t;
                    if (row < M) C[(size_t)row * Nout + col] = f2bf(fmaxf(acc[i][j][t] + bb, 0.f));
                }
            }
        }
    }
}

// ---- gathers ---------------------------------------------------------------

// layer 1 aggregate-first: one wave per (node, relation).
// agg4[d][r*256 + c] = ndst_r[d] * sum_e nsrc_r[s_e] * x[s_e][c]
__global__ void gather1_agg(const unsigned short* __restrict__ x_bf,
                            const int* __restrict__ rp, const int* __restrict__ e_src,
                            const float* __restrict__ nsrc, const float* __restrict__ ndst,
                            unsigned short* __restrict__ agg4, int N) {
    long w = (blockIdx.x * (long)blockDim.x + threadIdx.x) >> 6;
    int d = (int)(w >> 2);
    if (d >= N) return;
    int r = (int)(w & 3);
    int lane = threadIdx.x & 63;
    int beg = rp[(size_t)r * N + d], end = rp[(size_t)r * N + d + 1];
    const float* nsr = nsrc + (size_t)r * N;
    float4 acc = make_float4(0.f, 0.f, 0.f, 0.f);
    for (int e = beg; e < end; ++e) {
        int s = __builtin_nontemporal_load(e_src + e);
        float ns = nsr[s];                               // L2-hot 400KB table
        ushort4 v = *(const ushort4*)(x_bf + (size_t)s * DIN + lane * 4);
        acc.x += ns * bf2f(v.x); acc.y += ns * bf2f(v.y);
        acc.z += ns * bf2f(v.z); acc.w += ns * bf2f(v.w);
    }
    float nd = ndst[(size_t)r * N + d];
    ushort4 o = make_ushort4(f2bf(nd * acc.x), f2bf(nd * acc.y),
                             f2bf(nd * acc.z), f2bf(nd * acc.w));
    *(ushort4*)(agg4 + (size_t)d * (RELS * DIN) + r * DIN + lane * 4) = o;
}

// layer 2 project-first: one wave per dst node, all relations; out f32 + bias.
__global__ void gather2_fused(const unsigned short* __restrict__ hw4,
                              const int* __restrict__ rp, const int* __restrict__ e_src,
                              const float* __restrict__ ndst, const float* __restrict__ b2s,
                              float* __restrict__ out, int N) {
    int wid = (int)((blockIdx.x * (long)blockDim.x + threadIdx.x) >> 6);
    if (wid >= N) return;
    int lane = threadIdx.x & 63;
    float2 oacc = make_float2(0.f, 0.f);
#pragma unroll
    for (int r = 0; r < RELS; ++r) {
        int beg = rp[(size_t)r * N + wid], end = rp[(size_t)r * N + wid + 1];
        float2 acc = make_float2(0.f, 0.f);
        for (int e = beg; e < end; ++e) {
            int s = __builtin_nontemporal_load(e_src + e);
            ushort2 v = *(const ushort2*)(hw4 + (size_t)s * (RELS * DOUT) + r * DOUT + lane * 2);
            acc.x += bf2f(v.x); acc.y += bf2f(v.y);
        }
        float nd = ndst[(size_t)r * N + wid];
        oacc.x += nd * acc.x; oacc.y += nd * acc.y;
    }
    float2 b = *(const float2*)(b2s + lane * 2);
    *(float2*)(out + (size_t)wid * DOUT + lane * 2) = make_float2(oacc.x + b.x, oacc.y + b.y);
}

// ---- launch ------------------------------------------------------------------

extern "C" void kernel_launch(void* const* d_in, const int* in_sizes, int n_in,
                              void* d_out, int out_size, void* d_ws, size_t ws_size,
                              hipStream_t stream) {
    const float* x   = (const float*)d_in[0];
    const int*   src = (const int*)d_in[1];
    const int*   dst = (const int*)d_in[2];
    const float* W1  = (const float*)d_in[3];
    const float* b1  = (const float*)d_in[4];
    const float* W2  = (const float*)d_in[5];
    const float* b2  = (const float*)d_in[6];
    float* out = (float*)d_out;

    const int N = in_sizes[0] / DIN;       // 100000
    const int E = in_sizes[1] / RELS;      // 400000
    const int RN = RELS * N;

    // Workspace layout
    char* p = (char*)d_ws;
    int*   cnt_src = (int*)p;    p += (size_t)RN * sizeof(int);
    int*   cnt_dst = (int*)p;    p += (size_t)RN * sizeof(int);       // contiguous after cnt_src
    float* nsrc    = (float*)p;  p += (size_t)RN * sizeof(float);
    float* ndst    = (float*)p;  p += (size_t)RN * sizeof(float);     // contiguous after nsrc
    int*   row_ptr = (int*)p;    p += ((size_t)RN + 16) * sizeof(int);
    int*   cursor  = (int*)p;    p += (size_t)RN * sizeof(int);
    int*   e_src   = (int*)p;    p += (size_t)RELS * E * sizeof(int);
    int*   blk_sums= (int*)p;    p += 2048 * sizeof(int);
    float* b1s     = (float*)p;  p += DHID * sizeof(float);
    float* b2s     = (float*)p;  p += DOUT * sizeof(float);
    unsigned short* x_bf = (unsigned short*)p; p += (size_t)N * DIN * sizeof(short);
    unsigned short* w1t  = (unsigned short*)p; p += (size_t)RELS * DIN * DHID * sizeof(short);
    unsigned short* w2t  = (unsigned short*)p; p += (size_t)RELS * DHID * DOUT * sizeof(short);
    unsigned short* h_bf = (unsigned short*)p; p += (size_t)N * DHID * sizeof(short);
    unsigned short* agg4 = (unsigned short*)p; p += (size_t)N * RELS * DIN * sizeof(short);
    unsigned short* hw4  = agg4;   // alias: agg4 dead after gemm1

    // 0) dtype conversions + bias sums
    {
        long n8 = (long)N * DIN / 8;
        f32_to_bf16_kernel<<<(int)((n8 + 255) / 256), 256, 0, stream>>>(x, x_bf, n8);
        int t1 = RELS * DIN * DHID;
        w1_transpose_cat<<<(t1 + 255) / 256, 256, 0, stream>>>(W1, w1t, DIN, DHID);
        int t2 = RELS * DHID * DOUT;
        w2_transpose_cat<<<(t2 + 255) / 256, 256, 0, stream>>>(W2, w2t, DHID, DOUT);
        bias_sum_kernel<<<2, 256, 0, stream>>>(b1, b2, b1s, b2s);
    }

    // 1) degree histograms -> norms (both tables in one pass)
    hipMemsetAsync(cnt_src, 0, (size_t)2 * RN * sizeof(int), stream);
    {
        int total = RELS * E;
        hist_kernel<<<(total + 255) / 256, 256, 0, stream>>>(src, dst, cnt_src, cnt_dst, E, N);
        long ntot = (long)2 * RN;
        norm_kernel<<<(int)((ntot + 255) / 256), 256, 0, stream>>>(cnt_src, nsrc, ntot);
    }

    // 2) one global exclusive scan over all RELS*N dst-counts -> row_ptr[RN+1] (+cursor)
    const int nscan = (RN + 255) / 256;
    scan_block<<<nscan, 256, 0, stream>>>(cnt_dst, row_ptr, blk_sums, RN);
    scan_sums<<<1, 256, 0, stream>>>(blk_sums, nscan);
    scan_add<<<nscan, 256, 0, stream>>>(row_ptr, cursor, blk_sums, RN, RELS * E);
    {
        int total = RELS * E;
        fill_kernel<<<(total + 255) / 256, 256, 0, stream>>>(src, dst, cursor, e_src, E, N);
    }

    const int gx = (N + 127) / 128;

    // 3) layer 1 aggregate-first: gather x -> agg4 [N][1024], then concat GEMM
    //    [N,1024]@[1024,256] with bias+relu epilogue -> h_bf
    {
        long waves = (long)RELS * N;
        int blocks = (int)((waves + 3) / 4);
        gather1_agg<<<blocks, 256, 0, stream>>>(x_bf, row_ptr, e_src, nsrc, ndst, agg4, N);
        dim3 grid(gx, DHID / 128);
        gemm_bf16<1><<<grid, 256, 0, stream>>>(agg4, w1t, h_bf, N, DHID, RELS * DIN, b1s, 0, N);
    }

    // 4) layer 2 project-first: concat GEMM (Nout=512, nsrc epilogue) + gather
    {
        dim3 grid(gx, (RELS * DOUT) / 128);
        gemm_bf16<0><<<grid, 256, 0, stream>>>(h_bf, w2t, hw4, N, RELS * DOUT, DHID, nsrc, DOUT, N);
        int gblocks = (N + 3) / 4;
        gather2_fused<<<gblocks, 256, 0, stream>>>(hw4, row_ptr, e_src, ndst, b2s, out, N);
    }
}

// Round 7
// 860.059 us; speedup vs baseline: 1.2591x; 1.2591x over previous
//
#include <hip/hip_runtime.h>

// RGCN: 2-layer hetero GraphConv, R=4 relations.
// R1: CSR gather. R2: bf16 MFMA GEMM. R3: concat-GEMM + fused gathers.
// R4: layer-1 aggregate-first (gather x, then K=1024 GEMM).
// R5 REGRESSED (nsrc random lookup in gather1: +100MB L2-miss) -> reverted.
// R6: e_pack=(src,ns) int2 interleave (1x8B random store in fill, 1x8B seq
//     load in gather1), gather1 edge-loop unroll x2, cursor fused into scan.

#define RELS 4
#define DIN 256
#define DHID 256
#define DOUT 128

typedef short short8 __attribute__((ext_vector_type(8)));
typedef float f32x4 __attribute__((ext_vector_type(4)));

// ---- helpers --------------------------------------------------------------

__device__ __forceinline__ unsigned short f2bf(float f) {
    unsigned int u = __float_as_uint(f);
    u += 0x7FFFu + ((u >> 16) & 1u);   // round-to-nearest-even
    return (unsigned short)(u >> 16);
}
__device__ __forceinline__ float bf2f(unsigned short u) {
    return __uint_as_float(((unsigned int)u) << 16);
}

// ---- CSR build --------------------------------------------------------------

__global__ void hist_kernel(const int* __restrict__ src, const int* __restrict__ dst,
                            int* __restrict__ cnt_src, int* __restrict__ cnt_dst,
                            int E, int N) {
    int i = blockIdx.x * blockDim.x + threadIdx.x;
    if (i >= RELS * E) return;
    int r = i / E;
    atomicAdd(cnt_src + (size_t)r * N + src[i], 1);
    atomicAdd(cnt_dst + (size_t)r * N + dst[i], 1);
}

__global__ void norm_kernel(const int* __restrict__ cnt, float* __restrict__ nrm, long n) {
    long i = blockIdx.x * (long)blockDim.x + threadIdx.x;
    if (i >= n) return;
    nrm[i] = rsqrtf(fmaxf((float)cnt[i], 1.0f));
}

__global__ void scan_block(const int* __restrict__ counts, int* __restrict__ out,
                           int* __restrict__ blk_sums, int n) {
    __shared__ int sh[256];
    int i = blockIdx.x * 256 + threadIdx.x;
    int v = (i < n) ? counts[i] : 0;
    sh[threadIdx.x] = v;
    __syncthreads();
#pragma unroll
    for (int off = 1; off < 256; off <<= 1) {
        int t = (threadIdx.x >= off) ? sh[threadIdx.x - off] : 0;
        __syncthreads();
        sh[threadIdx.x] += t;
        __syncthreads();
    }
    if (i < n) out[i] = sh[threadIdx.x] - v;
    if (threadIdx.x == 255) blk_sums[blockIdx.x] = sh[255];
}

__global__ void scan_sums(int* __restrict__ bs, int nb) {
    __shared__ int sh[256];
    __shared__ int carry;
    if (threadIdx.x == 0) carry = 0;
    __syncthreads();
    for (int base = 0; base < nb; base += 256) {
        int i = base + threadIdx.x;
        int v = (i < nb) ? bs[i] : 0;
        sh[threadIdx.x] = v;
        __syncthreads();
#pragma unroll
        for (int off = 1; off < 256; off <<= 1) {
            int t = (threadIdx.x >= off) ? sh[threadIdx.x - off] : 0;
            __syncthreads();
            sh[threadIdx.x] += t;
            __syncthreads();
        }
        if (i < nb) bs[i] = sh[threadIdx.x] - v + carry;  // exclusive
        int tot = sh[255];
        __syncthreads();
        if (threadIdx.x == 255) carry += tot;
        __syncthreads();
    }
}

// writes row_ptr AND cursor (same values) — cursor_init launch eliminated
__global__ void scan_add(int* __restrict__ out, int* __restrict__ cursor,
                         const int* __restrict__ blk_sums, int n, int total) {
    int i = blockIdx.x * 256 + threadIdx.x;
    if (i < n) {
        int v = out[i] + blk_sums[blockIdx.x];
        out[i] = v;
        cursor[i] = v;
    }
    if (i == n - 1) out[n] = total;
}

// place (src, src-norm) into dst-sorted position as ONE 8B store
__global__ void fill_kernel(const int* __restrict__ src, const int* __restrict__ dst,
                            const float* __restrict__ nsrc,
                            int* __restrict__ cursor, int2* __restrict__ e_pack,
                            int E, int N) {
    int i = blockIdx.x * blockDim.x + threadIdx.x;
    if (i >= RELS * E) return;
    int r = i / E;
    int s = src[i];
    int pos = atomicAdd(cursor + (size_t)r * N + dst[i], 1);
    e_pack[pos] = make_int2(s, __float_as_int(nsrc[(size_t)r * N + s]));
}

// ---- dtype conversion --------------------------------------------------------

__global__ void f32_to_bf16_kernel(const float* __restrict__ in,
                                   unsigned short* __restrict__ out, long n8) {
    long i = blockIdx.x * (long)blockDim.x + threadIdx.x;
    if (i >= n8) return;
    const float4* ip = (const float4*)(in + i * 8);
    float4 v0 = ip[0], v1 = ip[1];
    ushort4 o0 = make_ushort4(f2bf(v0.x), f2bf(v0.y), f2bf(v0.z), f2bf(v0.w));
    ushort4 o1 = make_ushort4(f2bf(v1.x), f2bf(v1.y), f2bf(v1.z), f2bf(v1.w));
    ushort4* op = (ushort4*)(out + i * 8);
    op[0] = o0; op[1] = o1;
}

// W1 [R][K][Nout] f32 -> Wt [Nout][R*K] bf16  (K-concat layout for agg-first)
__global__ void w1_transpose_cat(const float* __restrict__ W, unsigned short* __restrict__ Wt,
                                 int K, int Nout) {
    int i = blockIdx.x * blockDim.x + threadIdx.x;
    int total = RELS * K * Nout;
    if (i >= total) return;
    int r = i / (K * Nout);
    int rem = i - r * (K * Nout);
    int k = rem / Nout, n = rem - k * Nout;
    Wt[(size_t)n * (RELS * K) + r * K + k] = f2bf(W[i]);
}

// W2 [R][K][Nout] f32 -> Wt [R*Nout][K] bf16  (N-concat layout for project-first)
__global__ void w2_transpose_cat(const float* __restrict__ W, unsigned short* __restrict__ Wt,
                                 int K, int Nout) {
    int i = blockIdx.x * blockDim.x + threadIdx.x;
    int total = RELS * K * Nout;
    if (i >= total) return;
    int r = i / (K * Nout);
    int rem = i - r * (K * Nout);
    int k = rem / Nout, n = rem - k * Nout;
    Wt[((size_t)r * Nout + n) * K + k] = f2bf(W[i]);
}

__global__ void bias_sum_kernel(const float* __restrict__ b1, const float* __restrict__ b2,
                                float* __restrict__ b1s, float* __restrict__ b2s) {
    int i = blockIdx.x * blockDim.x + threadIdx.x;
    if (i < DHID) {
        b1s[i] = b1[i] + b1[DHID + i] + b1[2 * DHID + i] + b1[3 * DHID + i];
    } else if (i < DHID + DOUT) {
        int c = i - DHID;
        b2s[c] = b2[c] + b2[DOUT + c] + b2[2 * DOUT + c] + b2[3 * DOUT + c];
    }
}

// ---- bf16 MFMA GEMM ---------------------------------------------------------
// BM=BN=128, BK=32, 256 threads (4 waves 2x2), 4x4 frags of 16x16x32/wave.
// LDS [128][32] bf16 per operand, XOR chunk swizzle (both-sides involution).
// MODE 0: C = bf16( acc * nsrc[rel][row] )          (layer-2 project-first)
// MODE 1: C = bf16( relu(acc + bias[col]) )         (layer-1 agg-first)

__device__ __forceinline__ void gload_lds16(const void* g, void* l) {
    __builtin_amdgcn_global_load_lds(
        (const __attribute__((address_space(1))) void*)g,
        (__attribute__((address_space(3))) void*)l, 16, 0, 0);
}

template <int MODE>
__global__ __launch_bounds__(256) void gemm_bf16(
    const unsigned short* __restrict__ A, const unsigned short* __restrict__ Bt,
    unsigned short* __restrict__ C, int M, int Nout, int K,
    const float* __restrict__ scale_or_bias, int cols_per_rel, int Nnodes) {
    __shared__ unsigned short smA[128 * 32];
    __shared__ unsigned short smB[128 * 32];
    const int tid = threadIdx.x;
    const int lane = tid & 63;
    const int wid = tid >> 6;
    const int wr = wid >> 1, wc = wid & 1;
    const int brow = blockIdx.x * 128, bcol = blockIdx.y * 128;

    f32x4 acc[4][4] = {};

    const int s = lane >> 4;
    const int rl = lane & 15;

    for (int k0 = 0; k0 < K; k0 += 32) {
#pragma unroll
        for (int q = 0; q < 2; ++q) {
            int c = q * 256 + tid;
            int cl = c ^ ((c >> 3) & 3);
            int row = cl >> 2, slot = cl & 3;
            int ga = brow + row; ga = ga < M ? ga : M - 1;
            size_t ldsoff = (size_t)(q * 256 + (tid & ~63)) * 16;
            gload_lds16(A + (size_t)ga * K + k0 + slot * 8, (char*)smA + ldsoff);
            gload_lds16(Bt + (size_t)(bcol + row) * K + k0 + slot * 8, (char*)smB + ldsoff);
        }
        asm volatile("s_waitcnt vmcnt(0)" ::: "memory");
        __syncthreads();

        short8 a[4], b[4];
#pragma unroll
        for (int i = 0; i < 4; ++i) {
            int r = wr * 64 + i * 16 + rl;
            int ch = r * 4 + (s ^ ((r >> 1) & 3));
            a[i] = *(const short8*)((const char*)smA + ch * 16);
        }
#pragma unroll
        for (int j = 0; j < 4; ++j) {
            int r = wc * 64 + j * 16 + rl;
            int ch = r * 4 + (s ^ ((r >> 1) & 3));
            b[j] = *(const short8*)((const char*)smB + ch * 16);
        }
#pragma unroll
        for (int i = 0; i < 4; ++i)
#pragma unroll
            for (int j = 0; j < 4; ++j)
                acc[i][j] = __builtin_amdgcn_mfma_f32_16x16x32_bf16(a[i], b[j], acc[i][j], 0, 0, 0);
        __syncthreads();
    }

    const int rq = lane >> 4;
    if (MODE == 0) {
        const int relid = bcol / cols_per_rel;
        const float* nsr = scale_or_bias + (size_t)relid * Nnodes;
#pragma unroll
        for (int i = 0; i < 4; ++i) {
            int rbase = brow + wr * 64 + i * 16 + rq * 4;
            float sc[4];
#pragma unroll
            for (int t = 0; t < 4; ++t) {
                int row = rbase + t;
                sc[t] = (row < M) ? nsr[row] : 0.f;
            }
#pragma unroll
            for (int j = 0; j < 4; ++j) {
                int col = bcol + wc * 64 + j * 16 + rl;
#pragma unroll
                for (int t = 0; t < 4; ++t) {
                    int row = rbase + t;
                    if (row < M) C[(size_t)row * Nout + col] = f2bf(acc[i][j][t] * sc[t]);
                }
            }
        }
    } else {
#pragma unroll
        for (int i = 0; i < 4; ++i) {
            int rbase = brow + wr * 64 + i * 16 + rq * 4;
#pragma unroll
            for (int j = 0; j < 4; ++j) {
                int col = bcol + wc * 64 + j * 16 + rl;
                float bb = scale_or_bias[col];
#pragma unroll
                for (int t = 0; t < 4; ++t) {
                    int row = rbase + t;
                    if (row < M) C[(size_t)row * Nout + col] = f2bf(fmaxf(acc[i][j][t] + bb, 0.f));
                }
            }
        }
    }
}

// ---- gathers ---------------------------------------------------------------

// layer 1 aggregate-first: one wave per (node, relation), edge loop unrolled x2.
// agg4[d][r*256 + c] = ndst_r[d] * sum_e ns_e * x[s_e][c]
__global__ void gather1_agg(const unsigned short* __restrict__ x_bf,
                            const int* __restrict__ rp, const int2* __restrict__ e_pack,
                            const float* __restrict__ ndst,
                            unsigned short* __restrict__ agg4, int N) {
    long w = (blockIdx.x * (long)blockDim.x + threadIdx.x) >> 6;
    int d = (int)(w >> 2);
    if (d >= N) return;
    int r = (int)(w & 3);
    int lane = threadIdx.x & 63;
    int beg = rp[(size_t)r * N + d], end = rp[(size_t)r * N + d + 1];
    float4 acc0 = make_float4(0.f, 0.f, 0.f, 0.f);
    float4 acc1 = make_float4(0.f, 0.f, 0.f, 0.f);
    int e = beg;
    for (; e + 1 < end; e += 2) {
        int2 p0 = e_pack[e];
        int2 p1 = e_pack[e + 1];
        ushort4 v0 = *(const ushort4*)(x_bf + (size_t)p0.x * DIN + lane * 4);
        ushort4 v1 = *(const ushort4*)(x_bf + (size_t)p1.x * DIN + lane * 4);
        float ns0 = __int_as_float(p0.y);
        float ns1 = __int_as_float(p1.y);
        acc0.x += ns0 * bf2f(v0.x); acc0.y += ns0 * bf2f(v0.y);
        acc0.z += ns0 * bf2f(v0.z); acc0.w += ns0 * bf2f(v0.w);
        acc1.x += ns1 * bf2f(v1.x); acc1.y += ns1 * bf2f(v1.y);
        acc1.z += ns1 * bf2f(v1.z); acc1.w += ns1 * bf2f(v1.w);
    }
    if (e < end) {
        int2 p0 = e_pack[e];
        ushort4 v0 = *(const ushort4*)(x_bf + (size_t)p0.x * DIN + lane * 4);
        float ns0 = __int_as_float(p0.y);
        acc0.x += ns0 * bf2f(v0.x); acc0.y += ns0 * bf2f(v0.y);
        acc0.z += ns0 * bf2f(v0.z); acc0.w += ns0 * bf2f(v0.w);
    }
    float nd = ndst[(size_t)r * N + d];
    ushort4 o = make_ushort4(f2bf(nd * (acc0.x + acc1.x)), f2bf(nd * (acc0.y + acc1.y)),
                             f2bf(nd * (acc0.z + acc1.z)), f2bf(nd * (acc0.w + acc1.w)));
    *(ushort4*)(agg4 + (size_t)d * (RELS * DIN) + r * DIN + lane * 4) = o;
}

// layer 2 project-first: one wave per dst node, all relations; out f32 + bias.
__global__ void gather2_fused(const unsigned short* __restrict__ hw4,
                              const int* __restrict__ rp, const int2* __restrict__ e_pack,
                              const float* __restrict__ ndst, const float* __restrict__ b2s,
                              float* __restrict__ out, int N) {
    int wid = (int)((blockIdx.x * (long)blockDim.x + threadIdx.x) >> 6);
    if (wid >= N) return;
    int lane = threadIdx.x & 63;
    float2 oacc = make_float2(0.f, 0.f);
#pragma unroll
    for (int r = 0; r < RELS; ++r) {
        int beg = rp[(size_t)r * N + wid], end = rp[(size_t)r * N + wid + 1];
        float2 acc = make_float2(0.f, 0.f);
        for (int e = beg; e < end; ++e) {
            int s = e_pack[e].x;
            ushort2 v = *(const ushort2*)(hw4 + (size_t)s * (RELS * DOUT) + r * DOUT + lane * 2);
            acc.x += bf2f(v.x); acc.y += bf2f(v.y);
        }
        float nd = ndst[(size_t)r * N + wid];
        oacc.x += nd * acc.x; oacc.y += nd * acc.y;
    }
    float2 b = *(const float2*)(b2s + lane * 2);
    *(float2*)(out + (size_t)wid * DOUT + lane * 2) = make_float2(oacc.x + b.x, oacc.y + b.y);
}

// ---- launch ------------------------------------------------------------------

extern "C" void kernel_launch(void* const* d_in, const int* in_sizes, int n_in,
                              void* d_out, int out_size, void* d_ws, size_t ws_size,
                              hipStream_t stream) {
    const float* x   = (const float*)d_in[0];
    const int*   src = (const int*)d_in[1];
    const int*   dst = (const int*)d_in[2];
    const float* W1  = (const float*)d_in[3];
    const float* b1  = (const float*)d_in[4];
    const float* W2  = (const float*)d_in[5];
    const float* b2  = (const float*)d_in[6];
    float* out = (float*)d_out;

    const int N = in_sizes[0] / DIN;       // 100000
    const int E = in_sizes[1] / RELS;      // 400000
    const int RN = RELS * N;

    // Workspace layout
    char* p = (char*)d_ws;
    int*   cnt_src = (int*)p;    p += (size_t)RN * sizeof(int);
    int*   cnt_dst = (int*)p;    p += (size_t)RN * sizeof(int);       // contiguous after cnt_src
    float* nsrc    = (float*)p;  p += (size_t)RN * sizeof(float);
    float* ndst    = (float*)p;  p += (size_t)RN * sizeof(float);     // contiguous after nsrc
    int*   row_ptr = (int*)p;    p += ((size_t)RN + 16) * sizeof(int);
    int*   cursor  = (int*)p;    p += (size_t)RN * sizeof(int);
    int2*  e_pack  = (int2*)p;   p += (size_t)RELS * E * sizeof(int2);
    int*   blk_sums= (int*)p;    p += 2048 * sizeof(int);
    float* b1s     = (float*)p;  p += DHID * sizeof(float);
    float* b2s     = (float*)p;  p += DOUT * sizeof(float);
    unsigned short* x_bf = (unsigned short*)p; p += (size_t)N * DIN * sizeof(short);
    unsigned short* w1t  = (unsigned short*)p; p += (size_t)RELS * DIN * DHID * sizeof(short);
    unsigned short* w2t  = (unsigned short*)p; p += (size_t)RELS * DHID * DOUT * sizeof(short);
    unsigned short* h_bf = (unsigned short*)p; p += (size_t)N * DHID * sizeof(short);
    unsigned short* agg4 = (unsigned short*)p; p += (size_t)N * RELS * DIN * sizeof(short);
    unsigned short* hw4  = agg4;   // alias: agg4 dead after gemm1

    // 0) dtype conversions + bias sums
    {
        long n8 = (long)N * DIN / 8;
        f32_to_bf16_kernel<<<(int)((n8 + 255) / 256), 256, 0, stream>>>(x, x_bf, n8);
        int t1 = RELS * DIN * DHID;
        w1_transpose_cat<<<(t1 + 255) / 256, 256, 0, stream>>>(W1, w1t, DIN, DHID);
        int t2 = RELS * DHID * DOUT;
        w2_transpose_cat<<<(t2 + 255) / 256, 256, 0, stream>>>(W2, w2t, DHID, DOUT);
        bias_sum_kernel<<<2, 256, 0, stream>>>(b1, b2, b1s, b2s);
    }

    // 1) degree histograms -> norms (both tables in one pass)
    hipMemsetAsync(cnt_src, 0, (size_t)2 * RN * sizeof(int), stream);
    {
        int total = RELS * E;
        hist_kernel<<<(total + 255) / 256, 256, 0, stream>>>(src, dst, cnt_src, cnt_dst, E, N);
        long ntot = (long)2 * RN;
        norm_kernel<<<(int)((ntot + 255) / 256), 256, 0, stream>>>(cnt_src, nsrc, ntot);
    }

    // 2) one global exclusive scan over all RELS*N dst-counts -> row_ptr[RN+1] (+cursor)
    const int nscan = (RN + 255) / 256;
    scan_block<<<nscan, 256, 0, stream>>>(cnt_dst, row_ptr, blk_sums, RN);
    scan_sums<<<1, 256, 0, stream>>>(blk_sums, nscan);
    scan_add<<<nscan, 256, 0, stream>>>(row_ptr, cursor, blk_sums, RN, RELS * E);
    {
        int total = RELS * E;
        fill_kernel<<<(total + 255) / 256, 256, 0, stream>>>(
            src, dst, nsrc, cursor, e_pack, E, N);
    }

    const int gx = (N + 127) / 128;

    // 3) layer 1 aggregate-first: gather x -> agg4 [N][1024], then concat GEMM
    //    [N,1024]@[1024,256] with bias+relu epilogue -> h_bf
    {
        long waves = (long)RELS * N;
        int blocks = (int)((waves + 3) / 4);
        gather1_agg<<<blocks, 256, 0, stream>>>(x_bf, row_ptr, e_pack, ndst, agg4, N);
        dim3 grid(gx, DHID / 128);
        gemm_bf16<1><<<grid, 256, 0, stream>>>(agg4, w1t, h_bf, N, DHID, RELS * DIN, b1s, 0, N);
    }

    // 4) layer 2 project-first: concat GEMM (Nout=512, nsrc epilogue) + gather
    {
        dim3 grid(gx, (RELS * DOUT) / 128);
        gemm_bf16<0><<<grid, 256, 0, stream>>>(h_bf, w2t, hw4, N, RELS * DOUT, DHID, nsrc, DOUT, N);
        int gblocks = (N + 3) / 4;
        gather2_fused<<<gblocks, 256, 0, stream>>>(hw4, row_ptr, e_pack, ndst, b2s, out, N);
    }
}

// Round 8
// 784.422 us; speedup vs baseline: 1.3806x; 1.0964x over previous
//
#include <hip/hip_runtime.h>

// RGCN: 2-layer hetero GraphConv, R=4 relations.
// R1: CSR gather. R2: bf16 MFMA GEMM. R3: concat-GEMM + fused gathers.
// R4: layer-1 aggregate-first (gather x, then K=1024 GEMM).
// R5 REGRESSED (nsrc random lookup in gather1) -> reverted in R6.
// R6: e_pack=(src,ns) int2 stream, gather unroll x2, cursor fused into scan.
// R7: gathers restructured to half-wave-per-edge with 16B/8B loads: half the
//     VMEM transactions, 4 row-loads in flight/wave, shfl_xor(32) final reduce.

#define RELS 4
#define DIN 256
#define DHID 256
#define DOUT 128

typedef short short8 __attribute__((ext_vector_type(8)));
typedef unsigned short ushort8 __attribute__((ext_vector_type(8)));
typedef float f32x4 __attribute__((ext_vector_type(4)));

// ---- helpers --------------------------------------------------------------

__device__ __forceinline__ unsigned short f2bf(float f) {
    unsigned int u = __float_as_uint(f);
    u += 0x7FFFu + ((u >> 16) & 1u);   // round-to-nearest-even
    return (unsigned short)(u >> 16);
}
__device__ __forceinline__ float bf2f(unsigned short u) {
    return __uint_as_float(((unsigned int)u) << 16);
}

// ---- CSR build --------------------------------------------------------------

__global__ void hist_kernel(const int* __restrict__ src, const int* __restrict__ dst,
                            int* __restrict__ cnt_src, int* __restrict__ cnt_dst,
                            int E, int N) {
    int i = blockIdx.x * blockDim.x + threadIdx.x;
    if (i >= RELS * E) return;
    int r = i / E;
    atomicAdd(cnt_src + (size_t)r * N + src[i], 1);
    atomicAdd(cnt_dst + (size_t)r * N + dst[i], 1);
}

__global__ void norm_kernel(const int* __restrict__ cnt, float* __restrict__ nrm, long n) {
    long i = blockIdx.x * (long)blockDim.x + threadIdx.x;
    if (i >= n) return;
    nrm[i] = rsqrtf(fmaxf((float)cnt[i], 1.0f));
}

__global__ void scan_block(const int* __restrict__ counts, int* __restrict__ out,
                           int* __restrict__ blk_sums, int n) {
    __shared__ int sh[256];
    int i = blockIdx.x * 256 + threadIdx.x;
    int v = (i < n) ? counts[i] : 0;
    sh[threadIdx.x] = v;
    __syncthreads();
#pragma unroll
    for (int off = 1; off < 256; off <<= 1) {
        int t = (threadIdx.x >= off) ? sh[threadIdx.x - off] : 0;
        __syncthreads();
        sh[threadIdx.x] += t;
        __syncthreads();
    }
    if (i < n) out[i] = sh[threadIdx.x] - v;
    if (threadIdx.x == 255) blk_sums[blockIdx.x] = sh[255];
}

__global__ void scan_sums(int* __restrict__ bs, int nb) {
    __shared__ int sh[256];
    __shared__ int carry;
    if (threadIdx.x == 0) carry = 0;
    __syncthreads();
    for (int base = 0; base < nb; base += 256) {
        int i = base + threadIdx.x;
        int v = (i < nb) ? bs[i] : 0;
        sh[threadIdx.x] = v;
        __syncthreads();
#pragma unroll
        for (int off = 1; off < 256; off <<= 1) {
            int t = (threadIdx.x >= off) ? sh[threadIdx.x - off] : 0;
            __syncthreads();
            sh[threadIdx.x] += t;
            __syncthreads();
        }
        if (i < nb) bs[i] = sh[threadIdx.x] - v + carry;  // exclusive
        int tot = sh[255];
        __syncthreads();
        if (threadIdx.x == 255) carry += tot;
        __syncthreads();
    }
}

// writes row_ptr AND cursor (same values) — cursor_init launch eliminated
__global__ void scan_add(int* __restrict__ out, int* __restrict__ cursor,
                         const int* __restrict__ blk_sums, int n, int total) {
    int i = blockIdx.x * 256 + threadIdx.x;
    if (i < n) {
        int v = out[i] + blk_sums[blockIdx.x];
        out[i] = v;
        cursor[i] = v;
    }
    if (i == n - 1) out[n] = total;
}

// place (src, src-norm) into dst-sorted position as ONE 8B store
__global__ void fill_kernel(const int* __restrict__ src, const int* __restrict__ dst,
                            const float* __restrict__ nsrc,
                            int* __restrict__ cursor, int2* __restrict__ e_pack,
                            int E, int N) {
    int i = blockIdx.x * blockDim.x + threadIdx.x;
    if (i >= RELS * E) return;
    int r = i / E;
    int s = src[i];
    int pos = atomicAdd(cursor + (size_t)r * N + dst[i], 1);
    e_pack[pos] = make_int2(s, __float_as_int(nsrc[(size_t)r * N + s]));
}

// ---- dtype conversion --------------------------------------------------------

__global__ void f32_to_bf16_kernel(const float* __restrict__ in,
                                   unsigned short* __restrict__ out, long n8) {
    long i = blockIdx.x * (long)blockDim.x + threadIdx.x;
    if (i >= n8) return;
    const float4* ip = (const float4*)(in + i * 8);
    float4 v0 = ip[0], v1 = ip[1];
    ushort4 o0 = make_ushort4(f2bf(v0.x), f2bf(v0.y), f2bf(v0.z), f2bf(v0.w));
    ushort4 o1 = make_ushort4(f2bf(v1.x), f2bf(v1.y), f2bf(v1.z), f2bf(v1.w));
    ushort4* op = (ushort4*)(out + i * 8);
    op[0] = o0; op[1] = o1;
}

// W1 [R][K][Nout] f32 -> Wt [Nout][R*K] bf16  (K-concat layout for agg-first)
__global__ void w1_transpose_cat(const float* __restrict__ W, unsigned short* __restrict__ Wt,
                                 int K, int Nout) {
    int i = blockIdx.x * blockDim.x + threadIdx.x;
    int total = RELS * K * Nout;
    if (i >= total) return;
    int r = i / (K * Nout);
    int rem = i - r * (K * Nout);
    int k = rem / Nout, n = rem - k * Nout;
    Wt[(size_t)n * (RELS * K) + r * K + k] = f2bf(W[i]);
}

// W2 [R][K][Nout] f32 -> Wt [R*Nout][K] bf16  (N-concat layout for project-first)
__global__ void w2_transpose_cat(const float* __restrict__ W, unsigned short* __restrict__ Wt,
                                 int K, int Nout) {
    int i = blockIdx.x * blockDim.x + threadIdx.x;
    int total = RELS * K * Nout;
    if (i >= total) return;
    int r = i / (K * Nout);
    int rem = i - r * (K * Nout);
    int k = rem / Nout, n = rem - k * Nout;
    Wt[((size_t)r * Nout + n) * K + k] = f2bf(W[i]);
}

__global__ void bias_sum_kernel(const float* __restrict__ b1, const float* __restrict__ b2,
                                float* __restrict__ b1s, float* __restrict__ b2s) {
    int i = blockIdx.x * blockDim.x + threadIdx.x;
    if (i < DHID) {
        b1s[i] = b1[i] + b1[DHID + i] + b1[2 * DHID + i] + b1[3 * DHID + i];
    } else if (i < DHID + DOUT) {
        int c = i - DHID;
        b2s[c] = b2[c] + b2[DOUT + c] + b2[2 * DOUT + c] + b2[3 * DOUT + c];
    }
}

// ---- bf16 MFMA GEMM ---------------------------------------------------------
// BM=BN=128, BK=32, 256 threads (4 waves 2x2), 4x4 frags of 16x16x32/wave.
// LDS [128][32] bf16 per operand, XOR chunk swizzle (both-sides involution).
// MODE 0: C = bf16( acc * nsrc[rel][row] )          (layer-2 project-first)
// MODE 1: C = bf16( relu(acc + bias[col]) )         (layer-1 agg-first)

__device__ __forceinline__ void gload_lds16(const void* g, void* l) {
    __builtin_amdgcn_global_load_lds(
        (const __attribute__((address_space(1))) void*)g,
        (__attribute__((address_space(3))) void*)l, 16, 0, 0);
}

template <int MODE>
__global__ __launch_bounds__(256) void gemm_bf16(
    const unsigned short* __restrict__ A, const unsigned short* __restrict__ Bt,
    unsigned short* __restrict__ C, int M, int Nout, int K,
    const float* __restrict__ scale_or_bias, int cols_per_rel, int Nnodes) {
    __shared__ unsigned short smA[128 * 32];
    __shared__ unsigned short smB[128 * 32];
    const int tid = threadIdx.x;
    const int lane = tid & 63;
    const int wid = tid >> 6;
    const int wr = wid >> 1, wc = wid & 1;
    const int brow = blockIdx.x * 128, bcol = blockIdx.y * 128;

    f32x4 acc[4][4] = {};

    const int s = lane >> 4;
    const int rl = lane & 15;

    for (int k0 = 0; k0 < K; k0 += 32) {
#pragma unroll
        for (int q = 0; q < 2; ++q) {
            int c = q * 256 + tid;
            int cl = c ^ ((c >> 3) & 3);
            int row = cl >> 2, slot = cl & 3;
            int ga = brow + row; ga = ga < M ? ga : M - 1;
            size_t ldsoff = (size_t)(q * 256 + (tid & ~63)) * 16;
            gload_lds16(A + (size_t)ga * K + k0 + slot * 8, (char*)smA + ldsoff);
            gload_lds16(Bt + (size_t)(bcol + row) * K + k0 + slot * 8, (char*)smB + ldsoff);
        }
        asm volatile("s_waitcnt vmcnt(0)" ::: "memory");
        __syncthreads();

        short8 a[4], b[4];
#pragma unroll
        for (int i = 0; i < 4; ++i) {
            int r = wr * 64 + i * 16 + rl;
            int ch = r * 4 + (s ^ ((r >> 1) & 3));
            a[i] = *(const short8*)((const char*)smA + ch * 16);
        }
#pragma unroll
        for (int j = 0; j < 4; ++j) {
            int r = wc * 64 + j * 16 + rl;
            int ch = r * 4 + (s ^ ((r >> 1) & 3));
            b[j] = *(const short8*)((const char*)smB + ch * 16);
        }
#pragma unroll
        for (int i = 0; i < 4; ++i)
#pragma unroll
            for (int j = 0; j < 4; ++j)
                acc[i][j] = __builtin_amdgcn_mfma_f32_16x16x32_bf16(a[i], b[j], acc[i][j], 0, 0, 0);
        __syncthreads();
    }

    const int rq = lane >> 4;
    if (MODE == 0) {
        const int relid = bcol / cols_per_rel;
        const float* nsr = scale_or_bias + (size_t)relid * Nnodes;
#pragma unroll
        for (int i = 0; i < 4; ++i) {
            int rbase = brow + wr * 64 + i * 16 + rq * 4;
            float sc[4];
#pragma unroll
            for (int t = 0; t < 4; ++t) {
                int row = rbase + t;
                sc[t] = (row < M) ? nsr[row] : 0.f;
            }
#pragma unroll
            for (int j = 0; j < 4; ++j) {
                int col = bcol + wc * 64 + j * 16 + rl;
#pragma unroll
                for (int t = 0; t < 4; ++t) {
                    int row = rbase + t;
                    if (row < M) C[(size_t)row * Nout + col] = f2bf(acc[i][j][t] * sc[t]);
                }
            }
        }
    } else {
#pragma unroll
        for (int i = 0; i < 4; ++i) {
            int rbase = brow + wr * 64 + i * 16 + rq * 4;
#pragma unroll
            for (int j = 0; j < 4; ++j) {
                int col = bcol + wc * 64 + j * 16 + rl;
                float bb = scale_or_bias[col];
#pragma unroll
                for (int t = 0; t < 4; ++t) {
                    int row = rbase + t;
                    if (row < M) C[(size_t)row * Nout + col] = f2bf(fmaxf(acc[i][j][t] + bb, 0.f));
                }
            }
        }
    }
}

// ---- gathers ---------------------------------------------------------------

// layer 1 aggregate-first: one wave per (node, relation); HALF-WAVE per edge.
// Each half (32 lanes x 16B = 512B) covers one x row; halves take alternating
// edges, unrolled x2 (4 rows in flight). Final combine via shfl_xor(32).
__global__ void gather1_agg(const unsigned short* __restrict__ x_bf,
                            const int* __restrict__ rp, const int2* __restrict__ e_pack,
                            const float* __restrict__ ndst,
                            unsigned short* __restrict__ agg4, int N) {
    long w = (blockIdx.x * (long)blockDim.x + threadIdx.x) >> 6;
    int d = (int)(w >> 2);
    if (d >= N) return;
    int r = (int)(w & 3);
    int lane = threadIdx.x & 63;
    int h = lane >> 5, l = lane & 31;
    int beg = rp[(size_t)r * N + d], end = rp[(size_t)r * N + d + 1];
    float acc0[8] = {}, acc1[8] = {};
    int e = beg + h;
    for (; e + 2 < end; e += 4) {     // this half's edges: e, e+2
        int2 p0 = e_pack[e];
        int2 p1 = e_pack[e + 2];
        ushort8 v0 = *(const ushort8*)(x_bf + (size_t)p0.x * DIN + l * 8);
        ushort8 v1 = *(const ushort8*)(x_bf + (size_t)p1.x * DIN + l * 8);
        float ns0 = __int_as_float(p0.y);
        float ns1 = __int_as_float(p1.y);
#pragma unroll
        for (int j = 0; j < 8; ++j) {
            acc0[j] += ns0 * bf2f(v0[j]);
            acc1[j] += ns1 * bf2f(v1[j]);
        }
    }
    if (e < end) {
        int2 p0 = e_pack[e];
        ushort8 v0 = *(const ushort8*)(x_bf + (size_t)p0.x * DIN + l * 8);
        float ns0 = __int_as_float(p0.y);
#pragma unroll
        for (int j = 0; j < 8; ++j) acc0[j] += ns0 * bf2f(v0[j]);
    }
    float nd = ndst[(size_t)r * N + d];
    ushort8 o;
#pragma unroll
    for (int j = 0; j < 8; ++j) {
        float v = acc0[j] + acc1[j];
        v += __shfl_xor(v, 32);
        o[j] = f2bf(nd * v);
    }
    if (h == 0)
        *(ushort8*)(agg4 + (size_t)d * (RELS * DIN) + r * DIN + l * 8) = o;
}

// layer 2 project-first: one wave per dst node; HALF-WAVE per edge (8B loads),
// unrolled x2, shfl_xor(32) combine, float4 store with bias.
__global__ void gather2_fused(const unsigned short* __restrict__ hw4,
                              const int* __restrict__ rp, const int2* __restrict__ e_pack,
                              const float* __restrict__ ndst, const float* __restrict__ b2s,
                              float* __restrict__ out, int N) {
    int wid = (int)((blockIdx.x * (long)blockDim.x + threadIdx.x) >> 6);
    if (wid >= N) return;
    int lane = threadIdx.x & 63;
    int h = lane >> 5, l = lane & 31;
    float oacc[4] = {};
#pragma unroll
    for (int r = 0; r < RELS; ++r) {
        int beg = rp[(size_t)r * N + wid], end = rp[(size_t)r * N + wid + 1];
        float acc0[4] = {}, acc1[4] = {};
        int e = beg + h;
        for (; e + 2 < end; e += 4) {
            int s0 = e_pack[e].x;
            int s1 = e_pack[e + 2].x;
            ushort4 v0 = *(const ushort4*)(hw4 + (size_t)s0 * (RELS * DOUT) + r * DOUT + l * 4);
            ushort4 v1 = *(const ushort4*)(hw4 + (size_t)s1 * (RELS * DOUT) + r * DOUT + l * 4);
            acc0[0] += bf2f(v0.x); acc0[1] += bf2f(v0.y); acc0[2] += bf2f(v0.z); acc0[3] += bf2f(v0.w);
            acc1[0] += bf2f(v1.x); acc1[1] += bf2f(v1.y); acc1[2] += bf2f(v1.z); acc1[3] += bf2f(v1.w);
        }
        if (e < end) {
            int s0 = e_pack[e].x;
            ushort4 v0 = *(const ushort4*)(hw4 + (size_t)s0 * (RELS * DOUT) + r * DOUT + l * 4);
            acc0[0] += bf2f(v0.x); acc0[1] += bf2f(v0.y); acc0[2] += bf2f(v0.z); acc0[3] += bf2f(v0.w);
        }
        float nd = ndst[(size_t)r * N + wid];
#pragma unroll
        for (int j = 0; j < 4; ++j) oacc[j] += nd * (acc0[j] + acc1[j]);
    }
#pragma unroll
    for (int j = 0; j < 4; ++j) oacc[j] += __shfl_xor(oacc[j], 32);
    if (h == 0) {
        float4 o = make_float4(oacc[0] + b2s[l * 4 + 0], oacc[1] + b2s[l * 4 + 1],
                               oacc[2] + b2s[l * 4 + 2], oacc[3] + b2s[l * 4 + 3]);
        *(float4*)(out + (size_t)wid * DOUT + l * 4) = o;
    }
}

// ---- launch ------------------------------------------------------------------

extern "C" void kernel_launch(void* const* d_in, const int* in_sizes, int n_in,
                              void* d_out, int out_size, void* d_ws, size_t ws_size,
                              hipStream_t stream) {
    const float* x   = (const float*)d_in[0];
    const int*   src = (const int*)d_in[1];
    const int*   dst = (const int*)d_in[2];
    const float* W1  = (const float*)d_in[3];
    const float* b1  = (const float*)d_in[4];
    const float* W2  = (const float*)d_in[5];
    const float* b2  = (const float*)d_in[6];
    float* out = (float*)d_out;

    const int N = in_sizes[0] / DIN;       // 100000
    const int E = in_sizes[1] / RELS;      // 400000
    const int RN = RELS * N;

    // Workspace layout
    char* p = (char*)d_ws;
    int*   cnt_src = (int*)p;    p += (size_t)RN * sizeof(int);
    int*   cnt_dst = (int*)p;    p += (size_t)RN * sizeof(int);       // contiguous after cnt_src
    float* nsrc    = (float*)p;  p += (size_t)RN * sizeof(float);
    float* ndst    = (float*)p;  p += (size_t)RN * sizeof(float);     // contiguous after nsrc
    int*   row_ptr = (int*)p;    p += ((size_t)RN + 16) * sizeof(int);
    int*   cursor  = (int*)p;    p += (size_t)RN * sizeof(int);
    int2*  e_pack  = (int2*)p;   p += (size_t)RELS * E * sizeof(int2);
    int*   blk_sums= (int*)p;    p += 2048 * sizeof(int);
    float* b1s     = (float*)p;  p += DHID * sizeof(float);
    float* b2s     = (float*)p;  p += DOUT * sizeof(float);
    unsigned short* x_bf = (unsigned short*)p; p += (size_t)N * DIN * sizeof(short);
    unsigned short* w1t  = (unsigned short*)p; p += (size_t)RELS * DIN * DHID * sizeof(short);
    unsigned short* w2t  = (unsigned short*)p; p += (size_t)RELS * DHID * DOUT * sizeof(short);
    unsigned short* h_bf = (unsigned short*)p; p += (size_t)N * DHID * sizeof(short);
    unsigned short* agg4 = (unsigned short*)p; p += (size_t)N * RELS * DIN * sizeof(short);
    unsigned short* hw4  = agg4;   // alias: agg4 dead after gemm1

    // 0) dtype conversions + bias sums
    {
        long n8 = (long)N * DIN / 8;
        f32_to_bf16_kernel<<<(int)((n8 + 255) / 256), 256, 0, stream>>>(x, x_bf, n8);
        int t1 = RELS * DIN * DHID;
        w1_transpose_cat<<<(t1 + 255) / 256, 256, 0, stream>>>(W1, w1t, DIN, DHID);
        int t2 = RELS * DHID * DOUT;
        w2_transpose_cat<<<(t2 + 255) / 256, 256, 0, stream>>>(W2, w2t, DHID, DOUT);
        bias_sum_kernel<<<2, 256, 0, stream>>>(b1, b2, b1s, b2s);
    }

    // 1) degree histograms -> norms (both tables in one pass)
    hipMemsetAsync(cnt_src, 0, (size_t)2 * RN * sizeof(int), stream);
    {
        int total = RELS * E;
        hist_kernel<<<(total + 255) / 256, 256, 0, stream>>>(src, dst, cnt_src, cnt_dst, E, N);
        long ntot = (long)2 * RN;
        norm_kernel<<<(int)((ntot + 255) / 256), 256, 0, stream>>>(cnt_src, nsrc, ntot);
    }

    // 2) one global exclusive scan over all RELS*N dst-counts -> row_ptr[RN+1] (+cursor)
    const int nscan = (RN + 255) / 256;
    scan_block<<<nscan, 256, 0, stream>>>(cnt_dst, row_ptr, blk_sums, RN);
    scan_sums<<<1, 256, 0, stream>>>(blk_sums, nscan);
    scan_add<<<nscan, 256, 0, stream>>>(row_ptr, cursor, blk_sums, RN, RELS * E);
    {
        int total = RELS * E;
        fill_kernel<<<(total + 255) / 256, 256, 0, stream>>>(
            src, dst, nsrc, cursor, e_pack, E, N);
    }

    const int gx = (N + 127) / 128;

    // 3) layer 1 aggregate-first: gather x -> agg4 [N][1024], then concat GEMM
    //    [N,1024]@[1024,256] with bias+relu epilogue -> h_bf
    {
        long waves = (long)RELS * N;
        int blocks = (int)((waves + 3) / 4);
        gather1_agg<<<blocks, 256, 0, stream>>>(x_bf, row_ptr, e_pack, ndst, agg4, N);
        dim3 grid(gx, DHID / 128);
        gemm_bf16<1><<<grid, 256, 0, stream>>>(agg4, w1t, h_bf, N, DHID, RELS * DIN, b1s, 0, N);
    }

    // 4) layer 2 project-first: concat GEMM (Nout=512, nsrc epilogue) + gather
    {
        dim3 grid(gx, (RELS * DOUT) / 128);
        gemm_bf16<0><<<grid, 256, 0, stream>>>(h_bf, w2t, hw4, N, RELS * DOUT, DHID, nsrc, DOUT, N);
        int gblocks = (N + 3) / 4;
        gather2_fused<<<gblocks, 256, 0, stream>>>(hw4, row_ptr, e_pack, ndst, b2s, out, N);
    }
}

// Round 9
// 778.912 us; speedup vs baseline: 1.3903x; 1.0071x over previous
//
#include <hip/hip_runtime.h>

// RGCN: 2-layer hetero GraphConv, R=4 relations.
// R1: CSR gather. R2: bf16 MFMA GEMM. R3: concat-GEMM + fused gathers.
// R4: layer-1 aggregate-first (gather x, then K=1024 GEMM).
// R5 REGRESSED (nsrc random lookup + NT fine-grain loads) -> reverted.
// R6: e_pack=(src,ns) int2 stream, unroll x2, cursor fused into scan.
// R7: half-wave-per-edge gathers (16B/8B loads, shfl_xor(32) reduce).
// R8: NT-STORE the streaming outputs (agg4, out) so x_bf/hw4 stay L3-resident
//     (FETCH 507MB was L3 self-eviction, not structural); prep kernels fused.

#define RELS 4
#define DIN 256
#define DHID 256
#define DOUT 128

typedef short short8 __attribute__((ext_vector_type(8)));
typedef unsigned short ushort8 __attribute__((ext_vector_type(8)));
typedef float f32x4 __attribute__((ext_vector_type(4)));

// ---- helpers --------------------------------------------------------------

__device__ __forceinline__ unsigned short f2bf(float f) {
    unsigned int u = __float_as_uint(f);
    u += 0x7FFFu + ((u >> 16) & 1u);   // round-to-nearest-even
    return (unsigned short)(u >> 16);
}
__device__ __forceinline__ float bf2f(unsigned short u) {
    return __uint_as_float(((unsigned int)u) << 16);
}

// ---- CSR build --------------------------------------------------------------

__global__ void hist_kernel(const int* __restrict__ src, const int* __restrict__ dst,
                            int* __restrict__ cnt_src, int* __restrict__ cnt_dst,
                            int E, int N) {
    int i = blockIdx.x * blockDim.x + threadIdx.x;
    if (i >= RELS * E) return;
    int r = i / E;
    atomicAdd(cnt_src + (size_t)r * N + src[i], 1);
    atomicAdd(cnt_dst + (size_t)r * N + dst[i], 1);
}

__global__ void norm_kernel(const int* __restrict__ cnt, float* __restrict__ nrm, long n) {
    long i = blockIdx.x * (long)blockDim.x + threadIdx.x;
    if (i >= n) return;
    nrm[i] = rsqrtf(fmaxf((float)cnt[i], 1.0f));
}

__global__ void scan_block(const int* __restrict__ counts, int* __restrict__ out,
                           int* __restrict__ blk_sums, int n) {
    __shared__ int sh[256];
    int i = blockIdx.x * 256 + threadIdx.x;
    int v = (i < n) ? counts[i] : 0;
    sh[threadIdx.x] = v;
    __syncthreads();
#pragma unroll
    for (int off = 1; off < 256; off <<= 1) {
        int t = (threadIdx.x >= off) ? sh[threadIdx.x - off] : 0;
        __syncthreads();
        sh[threadIdx.x] += t;
        __syncthreads();
    }
    if (i < n) out[i] = sh[threadIdx.x] - v;
    if (threadIdx.x == 255) blk_sums[blockIdx.x] = sh[255];
}

__global__ void scan_sums(int* __restrict__ bs, int nb) {
    __shared__ int sh[256];
    __shared__ int carry;
    if (threadIdx.x == 0) carry = 0;
    __syncthreads();
    for (int base = 0; base < nb; base += 256) {
        int i = base + threadIdx.x;
        int v = (i < nb) ? bs[i] : 0;
        sh[threadIdx.x] = v;
        __syncthreads();
#pragma unroll
        for (int off = 1; off < 256; off <<= 1) {
            int t = (threadIdx.x >= off) ? sh[threadIdx.x - off] : 0;
            __syncthreads();
            sh[threadIdx.x] += t;
            __syncthreads();
        }
        if (i < nb) bs[i] = sh[threadIdx.x] - v + carry;  // exclusive
        int tot = sh[255];
        __syncthreads();
        if (threadIdx.x == 255) carry += tot;
        __syncthreads();
    }
}

// writes row_ptr AND cursor (same values) — cursor_init launch eliminated
__global__ void scan_add(int* __restrict__ out, int* __restrict__ cursor,
                         const int* __restrict__ blk_sums, int n, int total) {
    int i = blockIdx.x * 256 + threadIdx.x;
    if (i < n) {
        int v = out[i] + blk_sums[blockIdx.x];
        out[i] = v;
        cursor[i] = v;
    }
    if (i == n - 1) out[n] = total;
}

// place (src, src-norm) into dst-sorted position as ONE 8B store
__global__ void fill_kernel(const int* __restrict__ src, const int* __restrict__ dst,
                            const float* __restrict__ nsrc,
                            int* __restrict__ cursor, int2* __restrict__ e_pack,
                            int E, int N) {
    int i = blockIdx.x * blockDim.x + threadIdx.x;
    if (i >= RELS * E) return;
    int r = i / E;
    int s = src[i];
    int pos = atomicAdd(cursor + (size_t)r * N + dst[i], 1);
    e_pack[pos] = make_int2(s, __float_as_int(nsrc[(size_t)r * N + s]));
}

// ---- fused prep: x->bf16, W1^T, W2^T, bias sums ------------------------------

__global__ void prep_fused(const float* __restrict__ x, const float* __restrict__ W1,
                           const float* __restrict__ W2, const float* __restrict__ b1,
                           const float* __restrict__ b2,
                           unsigned short* __restrict__ x_bf, unsigned short* __restrict__ w1t,
                           unsigned short* __restrict__ w2t,
                           float* __restrict__ b1s, float* __restrict__ b2s, long n8x) {
    const int T1 = RELS * DIN * DHID;
    const int T2 = RELS * DHID * DOUT;
    long i = blockIdx.x * (long)blockDim.x + threadIdx.x;
    if (i < n8x) {
        const float4* ip = (const float4*)(x + i * 8);
        float4 v0 = ip[0], v1 = ip[1];
        ushort4 o0 = make_ushort4(f2bf(v0.x), f2bf(v0.y), f2bf(v0.z), f2bf(v0.w));
        ushort4 o1 = make_ushort4(f2bf(v1.x), f2bf(v1.y), f2bf(v1.z), f2bf(v1.w));
        ushort4* op = (ushort4*)(x_bf + i * 8);
        op[0] = o0; op[1] = o1;
    } else if (i < n8x + T1) {
        int j = (int)(i - n8x);
        int r = j / (DIN * DHID);
        int rem = j - r * (DIN * DHID);
        int k = rem / DHID, n = rem - k * DHID;
        w1t[(size_t)n * (RELS * DIN) + r * DIN + k] = f2bf(W1[j]);
    } else if (i < n8x + T1 + T2) {
        int j = (int)(i - n8x - T1);
        int r = j / (DHID * DOUT);
        int rem = j - r * (DHID * DOUT);
        int k = rem / DOUT, n = rem - k * DOUT;
        w2t[((size_t)r * DOUT + n) * DHID + k] = f2bf(W2[j]);
    } else if (i < n8x + T1 + T2 + DHID + DOUT) {
        int c = (int)(i - n8x - T1 - T2);
        if (c < DHID) {
            b1s[c] = b1[c] + b1[DHID + c] + b1[2 * DHID + c] + b1[3 * DHID + c];
        } else {
            int cc = c - DHID;
            b2s[cc] = b2[cc] + b2[DOUT + cc] + b2[2 * DOUT + cc] + b2[3 * DOUT + cc];
        }
    }
}

// ---- bf16 MFMA GEMM ---------------------------------------------------------
// BM=BN=128, BK=32, 256 threads (4 waves 2x2), 4x4 frags of 16x16x32/wave.
// LDS [128][32] bf16 per operand, XOR chunk swizzle (both-sides involution).
// MODE 0: C = bf16( acc * nsrc[rel][row] )          (layer-2 project-first)
// MODE 1: C = bf16( relu(acc + bias[col]) )         (layer-1 agg-first)

__device__ __forceinline__ void gload_lds16(const void* g, void* l) {
    __builtin_amdgcn_global_load_lds(
        (const __attribute__((address_space(1))) void*)g,
        (__attribute__((address_space(3))) void*)l, 16, 0, 0);
}

template <int MODE>
__global__ __launch_bounds__(256) void gemm_bf16(
    const unsigned short* __restrict__ A, const unsigned short* __restrict__ Bt,
    unsigned short* __restrict__ C, int M, int Nout, int K,
    const float* __restrict__ scale_or_bias, int cols_per_rel, int Nnodes) {
    __shared__ unsigned short smA[128 * 32];
    __shared__ unsigned short smB[128 * 32];
    const int tid = threadIdx.x;
    const int lane = tid & 63;
    const int wid = tid >> 6;
    const int wr = wid >> 1, wc = wid & 1;
    const int brow = blockIdx.x * 128, bcol = blockIdx.y * 128;

    f32x4 acc[4][4] = {};

    const int s = lane >> 4;
    const int rl = lane & 15;

    for (int k0 = 0; k0 < K; k0 += 32) {
#pragma unroll
        for (int q = 0; q < 2; ++q) {
            int c = q * 256 + tid;
            int cl = c ^ ((c >> 3) & 3);
            int row = cl >> 2, slot = cl & 3;
            int ga = brow + row; ga = ga < M ? ga : M - 1;
            size_t ldsoff = (size_t)(q * 256 + (tid & ~63)) * 16;
            gload_lds16(A + (size_t)ga * K + k0 + slot * 8, (char*)smA + ldsoff);
            gload_lds16(Bt + (size_t)(bcol + row) * K + k0 + slot * 8, (char*)smB + ldsoff);
        }
        asm volatile("s_waitcnt vmcnt(0)" ::: "memory");
        __syncthreads();

        short8 a[4], b[4];
#pragma unroll
        for (int i = 0; i < 4; ++i) {
            int r = wr * 64 + i * 16 + rl;
            int ch = r * 4 + (s ^ ((r >> 1) & 3));
            a[i] = *(const short8*)((const char*)smA + ch * 16);
        }
#pragma unroll
        for (int j = 0; j < 4; ++j) {
            int r = wc * 64 + j * 16 + rl;
            int ch = r * 4 + (s ^ ((r >> 1) & 3));
            b[j] = *(const short8*)((const char*)smB + ch * 16);
        }
#pragma unroll
        for (int i = 0; i < 4; ++i)
#pragma unroll
            for (int j = 0; j < 4; ++j)
                acc[i][j] = __builtin_amdgcn_mfma_f32_16x16x32_bf16(a[i], b[j], acc[i][j], 0, 0, 0);
        __syncthreads();
    }

    const int rq = lane >> 4;
    if (MODE == 0) {
        const int relid = bcol / cols_per_rel;
        const float* nsr = scale_or_bias + (size_t)relid * Nnodes;
#pragma unroll
        for (int i = 0; i < 4; ++i) {
            int rbase = brow + wr * 64 + i * 16 + rq * 4;
            float sc[4];
#pragma unroll
            for (int t = 0; t < 4; ++t) {
                int row = rbase + t;
                sc[t] = (row < M) ? nsr[row] : 0.f;
            }
#pragma unroll
            for (int j = 0; j < 4; ++j) {
                int col = bcol + wc * 64 + j * 16 + rl;
#pragma unroll
                for (int t = 0; t < 4; ++t) {
                    int row = rbase + t;
                    if (row < M) C[(size_t)row * Nout + col] = f2bf(acc[i][j][t] * sc[t]);
                }
            }
        }
    } else {
#pragma unroll
        for (int i = 0; i < 4; ++i) {
            int rbase = brow + wr * 64 + i * 16 + rq * 4;
#pragma unroll
            for (int j = 0; j < 4; ++j) {
                int col = bcol + wc * 64 + j * 16 + rl;
                float bb = scale_or_bias[col];
#pragma unroll
                for (int t = 0; t < 4; ++t) {
                    int row = rbase + t;
                    if (row < M) C[(size_t)row * Nout + col] = f2bf(fmaxf(acc[i][j][t] + bb, 0.f));
                }
            }
        }
    }
}

// ---- gathers ---------------------------------------------------------------

// layer 1 aggregate-first: one wave per (node, relation); HALF-WAVE per edge.
// NT-store the agg4 stream so x_bf stays L3-resident.
__global__ void gather1_agg(const unsigned short* __restrict__ x_bf,
                            const int* __restrict__ rp, const int2* __restrict__ e_pack,
                            const float* __restrict__ ndst,
                            unsigned short* __restrict__ agg4, int N) {
    long w = (blockIdx.x * (long)blockDim.x + threadIdx.x) >> 6;
    int d = (int)(w >> 2);
    if (d >= N) return;
    int r = (int)(w & 3);
    int lane = threadIdx.x & 63;
    int h = lane >> 5, l = lane & 31;
    int beg = rp[(size_t)r * N + d], end = rp[(size_t)r * N + d + 1];
    float acc0[8] = {}, acc1[8] = {};
    int e = beg + h;
    for (; e + 2 < end; e += 4) {     // this half's edges: e, e+2
        int2 p0 = e_pack[e];
        int2 p1 = e_pack[e + 2];
        ushort8 v0 = *(const ushort8*)(x_bf + (size_t)p0.x * DIN + l * 8);
        ushort8 v1 = *(const ushort8*)(x_bf + (size_t)p1.x * DIN + l * 8);
        float ns0 = __int_as_float(p0.y);
        float ns1 = __int_as_float(p1.y);
#pragma unroll
        for (int j = 0; j < 8; ++j) {
            acc0[j] += ns0 * bf2f(v0[j]);
            acc1[j] += ns1 * bf2f(v1[j]);
        }
    }
    if (e < end) {
        int2 p0 = e_pack[e];
        ushort8 v0 = *(const ushort8*)(x_bf + (size_t)p0.x * DIN + l * 8);
        float ns0 = __int_as_float(p0.y);
#pragma unroll
        for (int j = 0; j < 8; ++j) acc0[j] += ns0 * bf2f(v0[j]);
    }
    float nd = ndst[(size_t)r * N + d];
    ushort8 o;
#pragma unroll
    for (int j = 0; j < 8; ++j) {
        float v = acc0[j] + acc1[j];
        v += __shfl_xor(v, 32);
        o[j] = f2bf(nd * v);
    }
    if (h == 0)
        __builtin_nontemporal_store(o, (ushort8*)(agg4 + (size_t)d * (RELS * DIN) + r * DIN + l * 8));
}

// layer 2 project-first: one wave per dst node; HALF-WAVE per edge (8B loads),
// NT-store the out stream so hw4 stays L3-resident.
__global__ void gather2_fused(const unsigned short* __restrict__ hw4,
                              const int* __restrict__ rp, const int2* __restrict__ e_pack,
                              const float* __restrict__ ndst, const float* __restrict__ b2s,
                              float* __restrict__ out, int N) {
    int wid = (int)((blockIdx.x * (long)blockDim.x + threadIdx.x) >> 6);
    if (wid >= N) return;
    int lane = threadIdx.x & 63;
    int h = lane >> 5, l = lane & 31;
    float oacc[4] = {};
#pragma unroll
    for (int r = 0; r < RELS; ++r) {
        int beg = rp[(size_t)r * N + wid], end = rp[(size_t)r * N + wid + 1];
        float acc0[4] = {}, acc1[4] = {};
        int e = beg + h;
        for (; e + 2 < end; e += 4) {
            int s0 = e_pack[e].x;
            int s1 = e_pack[e + 2].x;
            ushort4 v0 = *(const ushort4*)(hw4 + (size_t)s0 * (RELS * DOUT) + r * DOUT + l * 4);
            ushort4 v1 = *(const ushort4*)(hw4 + (size_t)s1 * (RELS * DOUT) + r * DOUT + l * 4);
            acc0[0] += bf2f(v0.x); acc0[1] += bf2f(v0.y); acc0[2] += bf2f(v0.z); acc0[3] += bf2f(v0.w);
            acc1[0] += bf2f(v1.x); acc1[1] += bf2f(v1.y); acc1[2] += bf2f(v1.z); acc1[3] += bf2f(v1.w);
        }
        if (e < end) {
            int s0 = e_pack[e].x;
            ushort4 v0 = *(const ushort4*)(hw4 + (size_t)s0 * (RELS * DOUT) + r * DOUT + l * 4);
            acc0[0] += bf2f(v0.x); acc0[1] += bf2f(v0.y); acc0[2] += bf2f(v0.z); acc0[3] += bf2f(v0.w);
        }
        float nd = ndst[(size_t)r * N + wid];
#pragma unroll
        for (int j = 0; j < 4; ++j) oacc[j] += nd * (acc0[j] + acc1[j]);
    }
#pragma unroll
    for (int j = 0; j < 4; ++j) oacc[j] += __shfl_xor(oacc[j], 32);
    if (h == 0) {
        f32x4 o;
        o[0] = oacc[0] + b2s[l * 4 + 0];
        o[1] = oacc[1] + b2s[l * 4 + 1];
        o[2] = oacc[2] + b2s[l * 4 + 2];
        o[3] = oacc[3] + b2s[l * 4 + 3];
        __builtin_nontemporal_store(o, (f32x4*)(out + (size_t)wid * DOUT + l * 4));
    }
}

// ---- launch ------------------------------------------------------------------

extern "C" void kernel_launch(void* const* d_in, const int* in_sizes, int n_in,
                              void* d_out, int out_size, void* d_ws, size_t ws_size,
                              hipStream_t stream) {
    const float* x   = (const float*)d_in[0];
    const int*   src = (const int*)d_in[1];
    const int*   dst = (const int*)d_in[2];
    const float* W1  = (const float*)d_in[3];
    const float* b1  = (const float*)d_in[4];
    const float* W2  = (const float*)d_in[5];
    const float* b2  = (const float*)d_in[6];
    float* out = (float*)d_out;

    const int N = in_sizes[0] / DIN;       // 100000
    const int E = in_sizes[1] / RELS;      // 400000
    const int RN = RELS * N;

    // Workspace layout
    char* p = (char*)d_ws;
    int*   cnt_src = (int*)p;    p += (size_t)RN * sizeof(int);
    int*   cnt_dst = (int*)p;    p += (size_t)RN * sizeof(int);       // contiguous after cnt_src
    float* nsrc    = (float*)p;  p += (size_t)RN * sizeof(float);
    float* ndst    = (float*)p;  p += (size_t)RN * sizeof(float);     // contiguous after nsrc
    int*   row_ptr = (int*)p;    p += ((size_t)RN + 16) * sizeof(int);
    int*   cursor  = (int*)p;    p += (size_t)RN * sizeof(int);
    int2*  e_pack  = (int2*)p;   p += (size_t)RELS * E * sizeof(int2);
    int*   blk_sums= (int*)p;    p += 2048 * sizeof(int);
    float* b1s     = (float*)p;  p += DHID * sizeof(float);
    float* b2s     = (float*)p;  p += DOUT * sizeof(float);
    unsigned short* x_bf = (unsigned short*)p; p += (size_t)N * DIN * sizeof(short);
    unsigned short* w1t  = (unsigned short*)p; p += (size_t)RELS * DIN * DHID * sizeof(short);
    unsigned short* w2t  = (unsigned short*)p; p += (size_t)RELS * DHID * DOUT * sizeof(short);
    unsigned short* h_bf = (unsigned short*)p; p += (size_t)N * DHID * sizeof(short);
    unsigned short* agg4 = (unsigned short*)p; p += (size_t)N * RELS * DIN * sizeof(short);
    unsigned short* hw4  = agg4;   // alias: agg4 dead after gemm1

    // 0) fused prep: x->bf16, W transposes, bias sums (one launch)
    {
        long n8x = (long)N * DIN / 8;
        long tot = n8x + RELS * DIN * DHID + RELS * DHID * DOUT + DHID + DOUT;
        prep_fused<<<(int)((tot + 255) / 256), 256, 0, stream>>>(
            x, W1, W2, b1, b2, x_bf, w1t, w2t, b1s, b2s, n8x);
    }

    // 1) degree histograms -> norms (both tables in one pass)
    hipMemsetAsync(cnt_src, 0, (size_t)2 * RN * sizeof(int), stream);
    {
        int total = RELS * E;
        hist_kernel<<<(total + 255) / 256, 256, 0, stream>>>(src, dst, cnt_src, cnt_dst, E, N);
        long ntot = (long)2 * RN;
        norm_kernel<<<(int)((ntot + 255) / 256), 256, 0, stream>>>(cnt_src, nsrc, ntot);
    }

    // 2) one global exclusive scan over all RELS*N dst-counts -> row_ptr[RN+1] (+cursor)
    const int nscan = (RN + 255) / 256;
    scan_block<<<nscan, 256, 0, stream>>>(cnt_dst, row_ptr, blk_sums, RN);
    scan_sums<<<1, 256, 0, stream>>>(blk_sums, nscan);
    scan_add<<<nscan, 256, 0, stream>>>(row_ptr, cursor, blk_sums, RN, RELS * E);
    {
        int total = RELS * E;
        fill_kernel<<<(total + 255) / 256, 256, 0, stream>>>(
            src, dst, nsrc, cursor, e_pack, E, N);
    }

    const int gx = (N + 127) / 128;

    // 3) layer 1 aggregate-first: gather x -> agg4 [N][1024], then concat GEMM
    //    [N,1024]@[1024,256] with bias+relu epilogue -> h_bf
    {
        long waves = (long)RELS * N;
        int blocks = (int)((waves + 3) / 4);
        gather1_agg<<<blocks, 256, 0, stream>>>(x_bf, row_ptr, e_pack, ndst, agg4, N);
        dim3 grid(gx, DHID / 128);
        gemm_bf16<1><<<grid, 256, 0, stream>>>(agg4, w1t, h_bf, N, DHID, RELS * DIN, b1s, 0, N);
    }

    // 4) layer 2 project-first: concat GEMM (Nout=512, nsrc epilogue) + gather
    {
        dim3 grid(gx, (RELS * DOUT) / 128);
        gemm_bf16<0><<<grid, 256, 0, stream>>>(h_bf, w2t, hw4, N, RELS * DOUT, DHID, nsrc, DOUT, N);
        int gblocks = (N + 3) / 4;
        gather2_fused<<<gblocks, 256, 0, stream>>>(hw4, row_ptr, e_pack, ndst, b2s, out, N);
    }
}